// Round 2
// baseline (106.178 us; speedup 1.0000x reference)
//
#include <hip/hip_runtime.h>

// SwitchReverseTriu: out[b,c,i] = rev[b] ? x[b,c,L-1-i] : x[b,c,i]
// x: (16, 32, 99681) fp32, rev: (16,) bool (int32 per harness convention)
//
// Row-structured kernel: one block per (row, quarter). 512 rows x BPR=4 = 2048 blocks.
// Forward rows: aligned float4 copy. Reversed rows: aligned float4 loads staged
// through wave-private LDS, reversed, aligned float4 stores. L odd => read/write
// 16B alignment can never coexist for a flip, hence the LDS shift-by-d stage.

#define L_DIM  99681
#define B_DIM  16
#define C_DIM  32
#define NROWS  (B_DIM * C_DIM)        // 512
#define NTOT   (NROWS * L_DIM)        // 51,036,672
#define BPR    4                      // blocks per row
#define NFULL  97                     // full 1024-float chunks per row (97*1024 = 99328)

__global__ __launch_bounds__(256) void SwitchReverseTriu_kernel(
    const float* __restrict__ x,
    const int* __restrict__ rev,
    float* __restrict__ out)
{
    // per-wave staging: 264 floats (1056 B, multiple of 16 so each wave's base
    // stays 16B-aligned for ds_write_b128)
    __shared__ float lds[4][264];

    const int blk = blockIdx.x;
    const int row = blk >> 2;               // BPR = 4
    const int bir = blk & (BPR - 1);
    const int b   = row >> 5;               // row / 32
    const int O   = row * L_DIM;            // flat float offset of row start
    // O mod 4 == row mod 4 (since L % 4 == 1); a = first output index with
    // (O + a) % 4 == 0
    const int a   = (4 - (row & 3)) & 3;
    const bool r  = rev[b] != 0;

    const int t = threadIdx.x;

    if (!r) {
        // ---- forward: pure aligned float4 copy ----
        for (int ch = bir; ch < NFULL; ch += BPR) {
            const int g = O + a + ch * 1024 + 4 * t;
            *reinterpret_cast<float4*>(out + g) =
                *reinterpret_cast<const float4*>(x + g);
        }
    } else {
        // ---- reversed: aligned loads -> wave-private LDS -> reversed aligned stores ----
        const int w = t >> 6;               // wave id in block
        const int j = t & 63;               // lane id
        float* Lw = lds[w];
        for (int ch = bir; ch < NFULL; ch += BPR) {
            const int i0w = a + ch * 1024 + (w << 8);   // first of this wave's 256 outputs
            const int R   = O + L_DIM - 256 - i0w;      // lowest input float needed
            const int d   = R & 3;                      // misalignment shift
            const int RA  = R - d;                      // aligned read base (>= O)

            // stage floats [RA, RA+255] (aligned float4 per lane)
            float4 v = *reinterpret_cast<const float4*>(x + RA + 4 * j);
            *reinterpret_cast<float4*>(Lw + 4 * j) = v;
            if (j == 0 && d) {
                // floats [RA+256, RA+259]: only [.. RA+255+d] are consumed; the
                // guarded tail protects the global last row from OOB reads.
                #pragma unroll
                for (int k = 0; k < 4; ++k) {
                    const int idx = RA + 256 + k;
                    Lw[256 + k] = (idx < NTOT) ? x[idx] : 0.0f;
                }
            }
            // wave-private region: intra-wave DS ordering + compiler lgkmcnt
            // suffice; no __syncthreads needed.
            const int q = d + 255 - 4 * j;
            float4 o;
            o.x = Lw[q];
            o.y = Lw[q - 1];
            o.z = Lw[q - 2];
            o.w = Lw[q - 3];
            const int g = O + i0w + 4 * j;
            *reinterpret_cast<float4*>(out + g) = o;
        }
    }

    // ---- scalar head [0,a) + tail [a+97*1024, L): 353 elements total ----
    if (bir == 0) {
        for (int i2 = t; i2 < 353; i2 += 256) {
            const int ii  = (i2 < a) ? i2 : i2 + NFULL * 1024;
            const int src = r ? (L_DIM - 1 - ii) : ii;
            out[O + ii] = x[O + src];
        }
    }
}

extern "C" void kernel_launch(void* const* d_in, const int* in_sizes, int n_in,
                              void* d_out, int out_size, void* d_ws, size_t ws_size,
                              hipStream_t stream) {
    const float* x  = (const float*)d_in[0];
    const int* rev  = (const int*)d_in[1];
    float* out      = (float*)d_out;

    SwitchReverseTriu_kernel<<<NROWS * BPR, 256, 0, stream>>>(x, rev, out);
}

// Round 3
// 94.327 us; speedup vs baseline: 1.1256x; 1.1256x over previous
//
#include <hip/hip_runtime.h>

// SwitchReverseTriu: out[b,c,i] = rev[b] ? x[b,c,L-1-i] : x[b,c,i]
// x: (16, 32, 99681) fp32, rev: (16,) bool (int32 per harness convention)
//
// One block per (row, quarter): 512 rows x BPR=4 = 2048 blocks x 256 threads.
// Forward rows: aligned float4 copy.
// Reversed rows: descending-chunk aligned float4 loads; lane j's reversed
//   output = select from {own chunk, lane j-1's chunk} via 4x __shfl_up(,1).
//   Shift d = (1-2a)&3 is wave-uniform (1 or 3) -> uniform branch, no LDS.
// Head/tail (353 scalars/row) handled by the bir==0 block.

#define L_DIM  99681
#define B_DIM  16
#define C_DIM  32
#define NROWS  (B_DIM * C_DIM)        // 512
#define NTOT   (NROWS * L_DIM)        // 51,036,672
#define BPR    4                      // blocks per row
#define NFULL  97                     // full 1024-float chunks per row

__global__ __launch_bounds__(256) void SwitchReverseTriu_kernel(
    const float* __restrict__ x,
    const int* __restrict__ rev,
    float* __restrict__ out)
{
    const int blk = blockIdx.x;
    const int row = blk >> 2;               // BPR = 4
    const int bir = blk & (BPR - 1);
    const int b   = row >> 5;               // row / 32
    const int O   = row * L_DIM;
    // first output index with (O + a) % 4 == 0  (L % 4 == 1 => O%4 == row%4)
    const int a   = (4 - (row & 3)) & 3;
    const bool r  = rev[b] != 0;
    const int t   = threadIdx.x;

    if (!r) {
        // ---- forward: pure aligned float4 copy ----
        for (int ch = bir; ch < NFULL; ch += BPR) {
            const int g = O + a + ch * 1024 + 4 * t;
            *reinterpret_cast<float4*>(out + g) =
                *reinterpret_cast<const float4*>(x + g);
        }
    } else {
        // ---- reversed: descending aligned float4 loads + lane-shift recombine ----
        const int w = t >> 6;               // wave id
        const int j = t & 63;               // lane id
        const int d = (1 - 2 * a) & 3;      // wave-uniform shift, always 1 or 3

        for (int ch = bir; ch < NFULL; ch += BPR) {
            const int i0w  = a + ch * 1024 + (w << 8);  // wave's first output idx
            const int W    = O + L_DIM - 256 - i0w;     // lowest input float needed
            const int base = W - d;                     // 16B-aligned (W%4 == d)

            // lane j holds input chunk (63-j): floats [base+4(63-j) .. +3]
            const float4 c =
                *reinterpret_cast<const float4*>(x + base + 4 * (63 - j));
            // lane 0 needs chunk 64 (floats base+256..259); in-bounds for all rows
            float4 extra;
            if (j == 0)
                extra = *reinterpret_cast<const float4*>(x + base + 256);

            // neighbor chunk (64-j) lives in lane j-1
            float n0 = __shfl_up(c.x, 1, 64);
            float n1 = __shfl_up(c.y, 1, 64);
            float n2 = __shfl_up(c.z, 1, 64);
            if (j == 0) { n0 = extra.x; n1 = extra.y; n2 = extra.z; }

            // e = [c.x c.y c.z c.w n0 n1 n2 n3]; out[m] = e[d+3-m]
            float4 o;
            if (d == 1) { o.x = n0;  o.y = c.w; o.z = c.z; o.w = c.y; }
            else        { o.x = n2;  o.y = n1;  o.z = n0;  o.w = c.w; }

            *reinterpret_cast<float4*>(out + O + i0w + 4 * j) = o;
        }
    }

    // ---- scalar head [0,a) + tail [a+97*1024, L): 353 elements total ----
    if (bir == 0) {
        for (int i2 = t; i2 < 353; i2 += 256) {
            const int ii  = (i2 < a) ? i2 : i2 + NFULL * 1024;
            const int src = r ? (L_DIM - 1 - ii) : ii;
            out[O + ii] = x[O + src];
        }
    }
}

extern "C" void kernel_launch(void* const* d_in, const int* in_sizes, int n_in,
                              void* d_out, int out_size, void* d_ws, size_t ws_size,
                              hipStream_t stream) {
    const float* x  = (const float*)d_in[0];
    const int* rev  = (const int*)d_in[1];
    float* out      = (float*)d_out;

    SwitchReverseTriu_kernel<<<NROWS * BPR, 256, 0, stream>>>(x, rev, out);
}

// Round 4
// 86.513 us; speedup vs baseline: 1.2273x; 1.0903x over previous
//
#include <hip/hip_runtime.h>

// SwitchReverseTriu: out[b,c,i] = rev[b] ? x[b,c,L-1-i] : x[b,c,i]
// x: (16, 32, 99681) fp32, rev: (16,) bool (int32 per harness convention)
//
// One block per (row, quarter): 512 rows x BPR=4 = 2048 blocks x 256 threads.
// Forward rows: aligned float4 copy, manually unrolled x4 (loads batched).
// Reversed rows: out4[i..i+3] = byte-reverse of the UNALIGNED float4 at
//   O+L-4-i. gfx950 supports dword-aligned dwordx4 loads, so this is one
//   16B load + register swizzle + one aligned 16B store. Unrolled x4.
// Head/tail (353 scalars/row) handled by the bir==0 block.

#define L_DIM  99681
#define B_DIM  16
#define C_DIM  32
#define NROWS  (B_DIM * C_DIM)        // 512
#define BPR    4                      // blocks per row
#define NFULL  97                     // full 1024-float chunks per row (97*1024=99328)

__global__ __launch_bounds__(256) void SwitchReverseTriu_kernel(
    const float* __restrict__ x,
    const int* __restrict__ rev,
    float* __restrict__ out)
{
    const int blk = blockIdx.x;
    const int row = blk >> 2;               // BPR = 4
    const int bir = blk & (BPR - 1);
    const int b   = row >> 5;               // row / 32
    const int O   = row * L_DIM;
    // first output index with (O + a) % 4 == 0  (L%4==1 => O%4 == row%4)
    const int a   = (4 - (row & 3)) & 3;
    const bool r  = rev[b] != 0;
    const int t   = threadIdx.x;

    // this block's chunks: ch = bir + 4k, k = 0..nk-1
    const int nk = (bir == 0) ? 25 : 24;

    if (!r) {
        // ---- forward: aligned float4 copy, 4 chunks per iteration ----
        int k = 0;
        for (; k + 4 <= nk; k += 4) {
            const int g0 = O + a + (bir + 4 * (k + 0)) * 1024 + 4 * t;
            const int g1 = g0 + 4 * 1024;
            const int g2 = g0 + 8 * 1024;
            const int g3 = g0 + 12 * 1024;
            float4 v0 = *reinterpret_cast<const float4*>(x + g0);
            float4 v1 = *reinterpret_cast<const float4*>(x + g1);
            float4 v2 = *reinterpret_cast<const float4*>(x + g2);
            float4 v3 = *reinterpret_cast<const float4*>(x + g3);
            *reinterpret_cast<float4*>(out + g0) = v0;
            *reinterpret_cast<float4*>(out + g1) = v1;
            *reinterpret_cast<float4*>(out + g2) = v2;
            *reinterpret_cast<float4*>(out + g3) = v3;
        }
        for (; k < nk; ++k) {               // remainder (bir==0 only: chunk 96)
            const int g = O + a + (bir + 4 * k) * 1024 + 4 * t;
            *reinterpret_cast<float4*>(out + g) =
                *reinterpret_cast<const float4*>(x + g);
        }
    } else {
        // ---- reversed: unaligned dwordx4 load + register reverse ----
        int k = 0;
        for (; k + 4 <= nk; k += 4) {
            const int i0 = a + (bir + 4 * (k + 0)) * 1024 + 4 * t;  // out idx (rel)
            const int i1 = i0 + 4 * 1024;
            const int i2 = i0 + 8 * 1024;
            const int i3 = i0 + 12 * 1024;
            float u0[4], u1[4], u2[4], u3[4];
            __builtin_memcpy(u0, x + (O + L_DIM - 4 - i0), 16);
            __builtin_memcpy(u1, x + (O + L_DIM - 4 - i1), 16);
            __builtin_memcpy(u2, x + (O + L_DIM - 4 - i2), 16);
            __builtin_memcpy(u3, x + (O + L_DIM - 4 - i3), 16);
            *reinterpret_cast<float4*>(out + O + i0) =
                make_float4(u0[3], u0[2], u0[1], u0[0]);
            *reinterpret_cast<float4*>(out + O + i1) =
                make_float4(u1[3], u1[2], u1[1], u1[0]);
            *reinterpret_cast<float4*>(out + O + i2) =
                make_float4(u2[3], u2[2], u2[1], u2[0]);
            *reinterpret_cast<float4*>(out + O + i3) =
                make_float4(u3[3], u3[2], u3[1], u3[0]);
        }
        for (; k < nk; ++k) {               // remainder (bir==0 only: chunk 96)
            const int i0 = a + (bir + 4 * k) * 1024 + 4 * t;
            float u[4];
            __builtin_memcpy(u, x + (O + L_DIM - 4 - i0), 16);
            *reinterpret_cast<float4*>(out + O + i0) =
                make_float4(u[3], u[2], u[1], u[0]);
        }
    }

    // ---- scalar head [0,a) + tail [a+97*1024, L): 353 elements total ----
    if (bir == 0) {
        for (int q = t; q < 353; q += 256) {
            const int ii  = (q < a) ? q : q + NFULL * 1024;
            const int src = r ? (L_DIM - 1 - ii) : ii;
            out[O + ii] = x[O + src];
        }
    }
}

extern "C" void kernel_launch(void* const* d_in, const int* in_sizes, int n_in,
                              void* d_out, int out_size, void* d_ws, size_t ws_size,
                              hipStream_t stream) {
    const float* x  = (const float*)d_in[0];
    const int* rev  = (const int*)d_in[1];
    float* out      = (float*)d_out;

    SwitchReverseTriu_kernel<<<NROWS * BPR, 256, 0, stream>>>(x, rev, out);
}

// Round 5
// 84.909 us; speedup vs baseline: 1.2505x; 1.0189x over previous
//
#include <hip/hip_runtime.h>

// SwitchReverseTriu: out[b,c,i] = rev[b] ? x[b,c,L-1-i] : x[b,c,i]
// x: (16, 32, 99681) fp32, rev: (16,) bool (int32 per harness convention)
//
// Grid-stride over float4 output indices (perfect load balance, device-wide
// sweeping window). Branchless body: one 16B load (aligned fwd / dword-aligned
// rev), v_cndmask swizzle, aligned 16B store. rev[] folded into a 16-bit
// ballot mask once. Rare channel-boundary crossings (248 of 12.76M) take a
// scalar patch branch. Hand-unrolled x4 for 4 loads in flight per thread.

#define L_DIM  99681
#define B_DIM  16
#define C_DIM  32
#define CL     (C_DIM * L_DIM)        // 3,189,792 floats per batch (mult of 4)
#define N_ELEM (B_DIM * CL)           // 51,036,672
#define N4     (N_ELEM / 4)           // 12,759,168

__device__ __forceinline__ float4 process_one(
    const float* __restrict__ x, unsigned mask16, int f4)
{
    const unsigned e0 = (unsigned)f4 * 4u;
    const unsigned b  = e0 / CL;                 // magic mul
    const unsigned m  = e0 - b * CL;
    const unsigned c  = m / L_DIM;               // magic mul
    const unsigned i  = m - c * L_DIM;
    const bool r      = (mask16 >> b) & 1u;
    const int chanBase = (int)(b * CL + c * L_DIM);

    // forward: src = chanBase + i (16B aligned). reversed fast: chanBase + L-4-i
    // (dword aligned). max() keeps the rare slow case in-bounds (overwritten).
    int roff = L_DIM - 4 - (int)i;
    roff = roff < 0 ? 0 : roff;
    const int src = chanBase + (r ? roff : (int)i);

    float u[4];
    __builtin_memcpy(u, x + src, 16);            // one global_load_dwordx4

    float4 o;
    o.x = r ? u[3] : u[0];
    o.y = r ? u[2] : u[1];
    o.z = r ? u[1] : u[2];
    o.w = r ? u[0] : u[3];

    if (__builtin_expect(r && (int)i > L_DIM - 4, 0)) {
        // output f4 straddles a channel boundary (never a batch boundary:
        // CL % 4 == 0). Recompute the 4 elements individually.
        float v0, v1, v2, v3;
        {
            unsigned mk = m + 0, ck = mk / L_DIM, ik = mk - ck * L_DIM;
            v0 = x[b * CL + ck * L_DIM + (L_DIM - 1 - ik)];
        }
        {
            unsigned mk = m + 1, ck = mk / L_DIM, ik = mk - ck * L_DIM;
            v1 = x[b * CL + ck * L_DIM + (L_DIM - 1 - ik)];
        }
        {
            unsigned mk = m + 2, ck = mk / L_DIM, ik = mk - ck * L_DIM;
            v2 = x[b * CL + ck * L_DIM + (L_DIM - 1 - ik)];
        }
        {
            unsigned mk = m + 3, ck = mk / L_DIM, ik = mk - ck * L_DIM;
            v3 = x[b * CL + ck * L_DIM + (L_DIM - 1 - ik)];
        }
        o = make_float4(v0, v1, v2, v3);
    }
    return o;
}

__global__ __launch_bounds__(256) void SwitchReverseTriu_kernel(
    const float* __restrict__ x,
    const int* __restrict__ rev,
    float* __restrict__ out)
{
    // rev[] -> 16-bit mask via one lane-load + one 64-lane ballot
    const int lane = threadIdx.x & 63;
    const int rv = rev[lane & 15];
    const unsigned long long bal = __ballot(rv != 0);
    const unsigned mask16 = (unsigned)(bal & 0xFFFFull);

    const int S = gridDim.x * blockDim.x;        // 524288
    int f4 = blockIdx.x * blockDim.x + threadIdx.x;

    // unrolled x4: 4 independent loads in flight before the 4 stores
    for (; f4 + 3 * S < N4; f4 += 4 * S) {
        float4 o0 = process_one(x, mask16, f4);
        float4 o1 = process_one(x, mask16, f4 + S);
        float4 o2 = process_one(x, mask16, f4 + 2 * S);
        float4 o3 = process_one(x, mask16, f4 + 3 * S);
        *reinterpret_cast<float4*>(out + (size_t)(f4)         * 4) = o0;
        *reinterpret_cast<float4*>(out + (size_t)(f4 + S)     * 4) = o1;
        *reinterpret_cast<float4*>(out + (size_t)(f4 + 2 * S) * 4) = o2;
        *reinterpret_cast<float4*>(out + (size_t)(f4 + 3 * S) * 4) = o3;
    }
    for (; f4 < N4; f4 += S) {
        float4 o = process_one(x, mask16, f4);
        *reinterpret_cast<float4*>(out + (size_t)f4 * 4) = o;
    }
}

extern "C" void kernel_launch(void* const* d_in, const int* in_sizes, int n_in,
                              void* d_out, int out_size, void* d_ws, size_t ws_size,
                              hipStream_t stream) {
    const float* x  = (const float*)d_in[0];
    const int* rev  = (const int*)d_in[1];
    float* out      = (float*)d_out;

    SwitchReverseTriu_kernel<<<2048, 256, 0, stream>>>(x, rev, out);
}

// Round 6
// 66.741 us; speedup vs baseline: 1.5909x; 1.2722x over previous
//
#include <hip/hip_runtime.h>

// SwitchReverseTriu: out[b,c,i] = rev[b] ? x[b,c,L-1-i] : x[b,c,i]
// x: (16, 32, 99681) fp32, rev: (16,) bool (int32 per harness convention)
//
// Round-1 champion structure (grid-stride f4, wave-uniform branch,
// forward = aligned dwordx4 copy, reversed = 4 scalar dword loads) plus:
//  - nontemporal dwordx4 stores (don't allocate output in L2/L3 -> input
//    stays L3-resident across graph replays; FETCH_SIZE is the tell)
//  - rev[] hoisted into a 16-bit ballot mask (no per-iter load+branch chain)
//  - manual x2 unroll, loads grouped before stores

#define L_DIM  99681
#define B_DIM  16
#define C_DIM  32
#define CL     (C_DIM * L_DIM)        // 3,189,792 floats per batch (mult of 4)
#define N_ELEM (B_DIM * CL)           // 51,036,672
#define N4     (N_ELEM / 4)           // 12,759,168

typedef float f32x4 __attribute__((ext_vector_type(4)));

__device__ __forceinline__ f32x4 process_one(
    const float* __restrict__ x, unsigned mask16, int f4)
{
    const unsigned e0 = (unsigned)f4 * 4u;
    const unsigned b  = e0 / CL;                 // magic mul
    const unsigned m  = e0 - b * CL;
    const bool r      = (mask16 >> b) & 1u;

    f32x4 o;
    if (!r) {
        const f32x4* p = reinterpret_cast<const f32x4*>(x + e0); // 16B aligned
        o = *p;
    } else {
        const unsigned c = m / L_DIM;            // magic mul
        const unsigned i = m - c * L_DIM;
        const float* __restrict__ xc = x + b * CL + c * L_DIM;
        if (__builtin_expect((int)i > L_DIM - 4, 0)) {
            // output quad straddles a channel boundary (never a batch
            // boundary: CL % 4 == 0) -> per-element recompute
            float v[4];
            #pragma unroll
            for (int k = 0; k < 4; ++k) {
                unsigned mk = m + k, ck = mk / L_DIM, ik = mk - ck * L_DIM;
                v[k] = x[b * CL + ck * L_DIM + (L_DIM - 1 - ik)];
            }
            o.x = v[0]; o.y = v[1]; o.z = v[2]; o.w = v[3];
        } else {
            const int s0 = L_DIM - 4 - (int)i;   // 4 independent dword loads
            o.x = xc[s0 + 3];
            o.y = xc[s0 + 2];
            o.z = xc[s0 + 1];
            o.w = xc[s0 + 0];
        }
    }
    return o;
}

__global__ __launch_bounds__(256) void SwitchReverseTriu_kernel(
    const float* __restrict__ x,
    const int* __restrict__ rev,
    float* __restrict__ out)
{
    // rev[] -> 16-bit mask via one lane-load + one 64-lane ballot
    const int lane = threadIdx.x & 63;
    const unsigned long long bal = __ballot(rev[lane & 15] != 0);
    const unsigned mask16 = (unsigned)(bal & 0xFFFFull);

    const int S = gridDim.x * blockDim.x;        // 524288
    int f4 = blockIdx.x * blockDim.x + threadIdx.x;

    // x2 unroll: both quads' loads issued before either store
    for (; f4 + S < N4; f4 += 2 * S) {
        f32x4 o0 = process_one(x, mask16, f4);
        f32x4 o1 = process_one(x, mask16, f4 + S);
        __builtin_nontemporal_store(o0, reinterpret_cast<f32x4*>(out) + f4);
        __builtin_nontemporal_store(o1, reinterpret_cast<f32x4*>(out) + f4 + S);
    }
    for (; f4 < N4; f4 += S) {
        f32x4 o = process_one(x, mask16, f4);
        __builtin_nontemporal_store(o, reinterpret_cast<f32x4*>(out) + f4);
    }
}

extern "C" void kernel_launch(void* const* d_in, const int* in_sizes, int n_in,
                              void* d_out, int out_size, void* d_ws, size_t ws_size,
                              hipStream_t stream) {
    const float* x  = (const float*)d_in[0];
    const int* rev  = (const int*)d_in[1];
    float* out      = (float*)d_out;

    SwitchReverseTriu_kernel<<<2048, 256, 0, stream>>>(x, rev, out);
}